// Round 5
// baseline (754.470 us; speedup 1.0000x reference)
//
#include <hip/hip_runtime.h>

#define NELEM 500000
#define NGP 4
#define NDOF 500000
#define HID 64

typedef _Float16 half2v __attribute__((ext_vector_type(2)));
typedef _Float16 half8v __attribute__((ext_vector_type(8)));
typedef float float4v __attribute__((ext_vector_type(4)));

__device__ __forceinline__ half2v pk(float a, float b) {
    return __builtin_bit_cast(half2v, __builtin_amdgcn_cvt_pkrtz(a, b));
}
__device__ __forceinline__ float fast_tanh(float x) {
    float cx = __builtin_amdgcn_fmed3f(x, -15.0f, 15.0f);
    float e = __expf(2.0f * cx);
    float r = __builtin_amdgcn_rcpf(e + 1.0f);
    return fmaf(-2.0f, r, 1.0f);
}
__device__ __forceinline__ float fdot2(half2v a, half2v b, float c) {
    return __builtin_amdgcn_fdot2(a, b, c, false);
}

// Cooperatively stage one gauss-point slice of B (256 elem x 24 floats = 24 KB)
// into LDS as 6 planes of float4[256]. Global reads: lane i covers element
// I/6, word4 I%6 -> consecutive lanes are consecutive 96B chunks (~16 lines
// per wave-instr instead of 64 with the per-thread strided pattern).
__device__ __forceinline__ void stage_B(const float4* __restrict__ B4, int e0,
                                        int g, int tid, float4* sB4) {
#pragma unroll
    for (int k = 0; k < 6; k++) {
        const int I = k * 256 + tid;
        const int eL = I / 6, w4 = I - 6 * eL;
        float4 v = make_float4(0.f, 0.f, 0.f, 0.f);
        if (e0 + eL < NELEM) v = B4[(size_t)(e0 + eL) * 24 + g * 6 + w4];
        sB4[w4 * 256 + eL] = v;
    }
}

// kernel1: strain -> MFMA MLP -> stress; EP either to ws (WS=1) or atomics.
template <int WS>
__global__ __launch_bounds__(256, 4) void fem_force_kernel(
    const float* __restrict__ u, const float* __restrict__ B,
    const float* __restrict__ Jacc, const float* __restrict__ gp_w,
    const int* __restrict__ conn, const float* __restrict__ weight1,
    const float* __restrict__ scales_inp, const float* __restrict__ limits_inp,
    const float* __restrict__ scales_grad, const float* __restrict__ limits_grad,
    const float* __restrict__ W1, const float* __restrict__ b1,
    const float* __restrict__ W2, const float* __restrict__ b2,
    const float* __restrict__ W3, const float* __restrict__ b3,
    float* __restrict__ EPout, float* __restrict__ F)
{
    __shared__ float4 sB4[6 * 256];  // 24 KB staging, reused per gauss point
    __shared__ uint   sX[1024];      // packed-f16 (x0,x1) per GP-row
    __shared__ float2 sG[4][256];    // MLP outputs, [gp][element] planes

    const int tid  = threadIdx.x;
    const int lane = tid & 63;
    const int wv   = tid >> 6;
    const int quad = lane >> 4;
    const int l15  = lane & 15;
    const int e0   = blockIdx.x * 256;
    const int e    = e0 + tid;
    const bool valid = (e < NELEM);
    const float4* B4 = (const float4*)B;

    const float SQ23 = 0.816496580927726f;
    const float si0 = scales_inp[0], si1 = scales_inp[1];
    const float li0 = limits_inp[0], li1 = limits_inp[1];
    const float isg0 = 1.0f / scales_grad[0], isg1 = 1.0f / scales_grad[1];
    const float lg0 = limits_grad[0], lg1 = limits_grad[1];
    const float b30 = b3[0], b31 = b3[1];

    // ---- per-lane weight fragments (registers for the whole kernel) ----
    half2v w1p[16];
    float  b1v[16];
#pragma unroll
    for (int f = 0; f < 2; f++)
#pragma unroll
        for (int j = 0; j < 8; j++) {
            const int k = f * 32 + quad * 8 + j;
            w1p[f * 8 + j] = pk(W1[k], W1[HID + k]);
            b1v[f * 8 + j] = b1[k];
        }
    half8v bf[4][2];
#pragma unroll
    for (int t = 0; t < 4; t++)
#pragma unroll
        for (int f = 0; f < 2; f++) {
            union { half8v v; uint uu[4]; } tmp;
#pragma unroll
            for (int jj = 0; jj < 4; jj++) {
                const int k0 = f * 32 + quad * 8 + 2 * jj;
                const int n  = t * 16 + l15;
                tmp.uu[jj] = __builtin_bit_cast(uint,
                    pk(W2[k0 * HID + n], W2[(k0 + 1) * HID + n]));
            }
            bf[t][f] = tmp.v;
        }
    float b2f[4], w3a[4], w3b[4];
#pragma unroll
    for (int t = 0; t < 4; t++) {
        const int n = t * 16 + l15;
        b2f[t] = b2[n];
        w3a[t] = W3[2 * n];
        w3b[t] = W3[2 * n + 1];
    }

    // ---- phase 1: strain invariants (B staged per-GP through LDS) ----
    float d00s[4], d11s[4], d01s[4], rds[4], wgt4[4];
    int ed[8];
    float ue[8];
    if (valid) {
        const int4 c4 = ((const int4*)conn)[e];
        ed[0] = 2 * c4.x; ed[1] = ed[0] + 1;
        ed[2] = 2 * c4.y; ed[3] = ed[2] + 1;
        ed[4] = 2 * c4.z; ed[5] = ed[4] + 1;
        ed[6] = 2 * c4.w; ed[7] = ed[6] + 1;
#pragma unroll
        for (int j = 0; j < 8; j++) ue[j] = weight1[ed[j]] * u[ed[j]];
        const float4 jv = ((const float4*)Jacc)[e];
        const float4 gw = ((const float4*)gp_w)[0];
        wgt4[0] = jv.x * gw.x; wgt4[1] = jv.y * gw.y;
        wgt4[2] = jv.z * gw.z; wgt4[3] = jv.w * gw.w;
    }

    uint xs[4] = {0u, 0u, 0u, 0u};
#pragma unroll
    for (int g = 0; g < NGP; g++) {
        stage_B(B4, e0, g, tid, sB4);
        __syncthreads();
        float s0 = 0.f, s1 = 0.f, s2 = 0.f;
        if (valid) {
#pragma unroll
            for (int w4 = 0; w4 < 6; w4++) {
                const float4 v = sB4[w4 * 256 + tid];
                const int j = w4 * 4;  // j..j+3 of the 24-float slice
                const float* vv = (const float*)&v;
#pragma unroll
                for (int q = 0; q < 4; q++) {
                    const int idx = j + q;          // 0..23 = [i][node] i=idx/8
                    const float uu = ue[idx & 7];
                    if (idx < 8)       s0 = fmaf(vv[q], uu, s0);
                    else if (idx < 16) s1 = fmaf(vv[q], uu, s1);
                    else               s2 = fmaf(vv[q], uu, s2);
                }
            }
        }
        __syncthreads();
        const float ev  = s0 + s1;
        const float ev3 = ev * (1.0f / 3.0f);
        const float d00 = s0 - ev3, d11 = s1 - ev3, d22 = -ev3, d01 = 0.5f * s2;
        const float det = sqrtf(d00 * d00 + d11 * d11 + d22 * d22 + 2.0f * d01 * d01);
        const float rd  = __builtin_amdgcn_rcpf(det);
        const float es  = det * SQ23;
        d00s[g] = d00; d11s[g] = d11; d01s[g] = d01; rds[g] = rd;
        if (valid) xs[g] = __builtin_bit_cast(uint, pk(fmaf(ev, si0, li0), fmaf(es, si1, li1)));
    }
    ((uint4*)sX)[tid] = make_uint4(xs[0], xs[1], xs[2], xs[3]);
    __syncthreads();

    // ---- phase 2: wave-level MFMA MLP (unchanged from round 4) ----
#pragma unroll 1
    for (int rt = 0; rt < 16; rt++) {
        const int tb = wv * 256 + rt * 16;
        const half2v xp = __builtin_bit_cast(half2v, sX[tb + l15]);
        union { half8v v; uint uu[4]; } A0, A1;
#pragma unroll
        for (int jj = 0; jj < 4; jj++) {
            const float t0 = fast_tanh(fdot2(xp, w1p[2 * jj],     b1v[2 * jj]));
            const float t1 = fast_tanh(fdot2(xp, w1p[2 * jj + 1], b1v[2 * jj + 1]));
            const float t2 = fast_tanh(fdot2(xp, w1p[8 + 2 * jj],     b1v[8 + 2 * jj]));
            const float t3 = fast_tanh(fdot2(xp, w1p[8 + 2 * jj + 1], b1v[8 + 2 * jj + 1]));
            A0.uu[jj] = __builtin_bit_cast(uint, pk(t0, t1));
            A1.uu[jj] = __builtin_bit_cast(uint, pk(t2, t3));
        }
        float s0[4] = {0.f, 0.f, 0.f, 0.f};
        float s1[4] = {0.f, 0.f, 0.f, 0.f};
#pragma unroll
        for (int t = 0; t < 4; t++) {
            float4v c = {b2f[t], b2f[t], b2f[t], b2f[t]};
            c = __builtin_amdgcn_mfma_f32_16x16x32_f16(A0.v, bf[t][0], c, 0, 0, 0);
            c = __builtin_amdgcn_mfma_f32_16x16x32_f16(A1.v, bf[t][1], c, 0, 0, 0);
#pragma unroll
            for (int reg = 0; reg < 4; reg++) {
                const float h = fast_tanh(c[reg]);
                s0[reg] = fmaf(h, w3a[t], s0[reg]);
                s1[reg] = fmaf(h, w3b[t], s1[reg]);
            }
        }
#pragma unroll
        for (int mask = 1; mask < 16; mask <<= 1) {
#pragma unroll
            for (int reg = 0; reg < 4; reg++) {
                s0[reg] += __shfl_xor(s0[reg], mask, 64);
                s1[reg] += __shfl_xor(s1[reg], mask, 64);
            }
        }
        if (l15 < 4) {
            float a = s0[0], b = s1[0];
            if (l15 == 1) { a = s0[1]; b = s1[1]; }
            if (l15 == 2) { a = s0[2]; b = s1[2]; }
            if (l15 == 3) { a = s0[3]; b = s1[3]; }
            const int gi = tb + quad * 4 + l15;
            sG[gi & 3][gi >> 2] = make_float2(a, b);
        }
    }
    __syncthreads();

    // ---- phase 3: stress -> E_P (B re-staged per-GP; L3-resident) ----
    float EP[8] = {0.f, 0.f, 0.f, 0.f, 0.f, 0.f, 0.f, 0.f};
#pragma unroll
    for (int g = 0; g < NGP; g++) {
        float2 gv = make_float2(0.f, 0.f);
        if (valid) gv = sG[g][tid];
        __syncthreads();   // sG reads done before sB4 overwrite? (separate arrays; barrier paces staging)
        stage_B(B4, e0, g, tid, sB4);
        __syncthreads();
        if (valid) {
            const float p = (gv.x + b30 - lg0) * isg0;
            const float q = (gv.y + b31 - lg1) * isg1;
            const float crd = SQ23 * q * rds[g];
            const float f0 = fmaf(crd, d00s[g], p) * wgt4[g];
            const float f1 = fmaf(crd, d11s[g], p) * wgt4[g];
            const float f2 = (crd * d01s[g]) * wgt4[g];
            const float4 v0 = sB4[0 * 256 + tid], v1 = sB4[1 * 256 + tid];
            const float4 v2 = sB4[2 * 256 + tid], v3 = sB4[3 * 256 + tid];
            const float4 v4 = sB4[4 * 256 + tid], v5 = sB4[5 * 256 + tid];
            EP[0] = fmaf(v0.x, f0, fmaf(v2.x, f1, fmaf(v4.x, f2, EP[0])));
            EP[1] = fmaf(v0.y, f0, fmaf(v2.y, f1, fmaf(v4.y, f2, EP[1])));
            EP[2] = fmaf(v0.z, f0, fmaf(v2.z, f1, fmaf(v4.z, f2, EP[2])));
            EP[3] = fmaf(v0.w, f0, fmaf(v2.w, f1, fmaf(v4.w, f2, EP[3])));
            EP[4] = fmaf(v1.x, f0, fmaf(v3.x, f1, fmaf(v5.x, f2, EP[4])));
            EP[5] = fmaf(v1.y, f0, fmaf(v3.y, f1, fmaf(v5.y, f2, EP[5])));
            EP[6] = fmaf(v1.z, f0, fmaf(v3.z, f1, fmaf(v5.z, f2, EP[6])));
            EP[7] = fmaf(v1.w, f0, fmaf(v3.w, f1, fmaf(v5.w, f2, EP[7])));
        }
        __syncthreads();
    }

    if (valid) {
        if (WS) {
            float4* o = (float4*)(EPout + (size_t)e * 8);
            o[0] = make_float4(EP[0], EP[1], EP[2], EP[3]);
            o[1] = make_float4(EP[4], EP[5], EP[6], EP[7]);
        } else {
#pragma unroll
            for (int j = 0; j < 8; j++) atomicAdd(&F[ed[j]], EP[j]);
        }
    }
}

// kernel2: pure scatter — isolates the atomic-fabric cost, max occupancy.
__global__ __launch_bounds__(256, 8) void scatter_kernel(
    const int* __restrict__ conn, const float* __restrict__ EPin,
    float* __restrict__ F)
{
    const int e = blockIdx.x * 256 + threadIdx.x;
    if (e >= NELEM) return;
    const int4 c4 = ((const int4*)conn)[e];
    const float4 a = ((const float4*)EPin)[2 * e];
    const float4 b = ((const float4*)EPin)[2 * e + 1];
    atomicAdd(&F[2 * c4.x],     a.x);
    atomicAdd(&F[2 * c4.x + 1], a.y);
    atomicAdd(&F[2 * c4.y],     a.z);
    atomicAdd(&F[2 * c4.y + 1], a.w);
    atomicAdd(&F[2 * c4.z],     b.x);
    atomicAdd(&F[2 * c4.z + 1], b.y);
    atomicAdd(&F[2 * c4.w],     b.z);
    atomicAdd(&F[2 * c4.w + 1], b.w);
}

extern "C" void kernel_launch(void* const* d_in, const int* in_sizes, int n_in,
                              void* d_out, int out_size, void* d_ws, size_t ws_size,
                              hipStream_t stream) {
    const float* u           = (const float*)d_in[0];
    const float* B           = (const float*)d_in[1];
    const float* Jacc        = (const float*)d_in[2];
    const float* gp_w        = (const float*)d_in[3];
    const int*   conn        = (const int*)  d_in[4];
    const float* weight1     = (const float*)d_in[5];
    const float* scales_inp  = (const float*)d_in[6];
    const float* limits_inp  = (const float*)d_in[7];
    const float* scales_grad = (const float*)d_in[8];
    const float* limits_grad = (const float*)d_in[9];
    const float* W1          = (const float*)d_in[10];
    const float* b1          = (const float*)d_in[11];
    const float* W2          = (const float*)d_in[12];
    const float* b2          = (const float*)d_in[13];
    const float* W3          = (const float*)d_in[14];
    const float* b3          = (const float*)d_in[15];
    float* F = (float*)d_out;

    (void)hipMemsetAsync(d_out, 0, sizeof(float) * NDOF, stream);

    const int grid = (NELEM + 255) / 256;
    const bool use_ws = (ws_size >= (size_t)NELEM * 8 * sizeof(float));
    if (use_ws) {
        float* EP = (float*)d_ws;
        fem_force_kernel<1><<<grid, 256, 0, stream>>>(
            u, B, Jacc, gp_w, conn, weight1, scales_inp, limits_inp,
            scales_grad, limits_grad, W1, b1, W2, b2, W3, b3, EP, F);
        scatter_kernel<<<grid, 256, 0, stream>>>(conn, EP, F);
    } else {
        fem_force_kernel<0><<<grid, 256, 0, stream>>>(
            u, B, Jacc, gp_w, conn, weight1, scales_inp, limits_inp,
            scales_grad, limits_grad, W1, b1, W2, b2, W3, b3, nullptr, F);
    }
}

// Round 6
// 534.887 us; speedup vs baseline: 1.4105x; 1.4105x over previous
//
#include <hip/hip_runtime.h>

#define NELEM 500000
#define NGP 4
#define NDOF 500000
#define HID 64

typedef _Float16 half2v __attribute__((ext_vector_type(2)));
typedef _Float16 half8v __attribute__((ext_vector_type(8)));
typedef float float4v __attribute__((ext_vector_type(4)));
typedef float float2v __attribute__((ext_vector_type(2)));

__device__ __forceinline__ half2v pk(float a, float b) {
    return __builtin_bit_cast(half2v, __builtin_amdgcn_cvt_pkrtz(a, b));
}
__device__ __forceinline__ float fast_tanh(float x) {
    float cx = __builtin_amdgcn_fmed3f(x, -15.0f, 15.0f);
    float e = __expf(2.0f * cx);
    float r = __builtin_amdgcn_rcpf(e + 1.0f);
    return fmaf(-2.0f, r, 1.0f);
}
__device__ __forceinline__ float fdot2(half2v a, half2v b, float c) {
    return __builtin_amdgcn_fdot2(a, b, c, false);
}

// F[2n],F[2n+1] are adjacent: try packed f32x2 atomic (halves request count);
// guarded so absence on this clang just falls back to two scalar atomics.
__device__ __forceinline__ void atomic_add2(float* p, float a, float b) {
#if __has_builtin(__builtin_amdgcn_global_atomic_fadd_v2f32)
    typedef __attribute__((address_space(1))) float2v gf2;
    float2v v = {a, b};
    (void)__builtin_amdgcn_global_atomic_fadd_v2f32((gf2*)p, v);
#else
    atomicAdd(p, a);
    atomicAdd(p + 1, b);
#endif
}

// Round-4 structure (fused atomics, per-thread B reads, MFMA layer-2).
// launch_bounds(256,3): VGPR cap ~170 (kernel needs ~112 -> no spill), and
// the 2nd arg acts as the residency tier -> 12 waves/CU (r4's (256,2) gave 8).
__global__ __launch_bounds__(256, 3) void fem_force_kernel(
    const float* __restrict__ u, const float* __restrict__ B,
    const float* __restrict__ Jacc, const float* __restrict__ gp_w,
    const int* __restrict__ conn, const float* __restrict__ weight1,
    const float* __restrict__ scales_inp, const float* __restrict__ limits_inp,
    const float* __restrict__ scales_grad, const float* __restrict__ limits_grad,
    const float* __restrict__ W1, const float* __restrict__ b1,
    const float* __restrict__ W2, const float* __restrict__ b2,
    const float* __restrict__ W3, const float* __restrict__ b3,
    float* __restrict__ F)
{
    __shared__ uint   sX[1024];      // packed-f16 (x0,x1) per GP-row
    __shared__ float2 sG[4][256];    // MLP outputs, [gp][element] planes

    const int tid  = threadIdx.x;
    const int lane = tid & 63;
    const int wv   = tid >> 6;
    const int quad = lane >> 4;
    const int l15  = lane & 15;
    const int e    = blockIdx.x * 256 + tid;
    const bool valid = (e < NELEM);

    const float SQ23 = 0.816496580927726f;
    const float si0 = scales_inp[0], si1 = scales_inp[1];
    const float li0 = limits_inp[0], li1 = limits_inp[1];
    const float isg0 = 1.0f / scales_grad[0], isg1 = 1.0f / scales_grad[1];
    const float lg0 = limits_grad[0], lg1 = limits_grad[1];
    const float b30 = b3[0], b31 = b3[1];

    // ---- per-lane weight fragments (loaded once, registers for the kernel) ----
    half2v w1p[16];
    float  b1v[16];
#pragma unroll
    for (int f = 0; f < 2; f++)
#pragma unroll
        for (int j = 0; j < 8; j++) {
            const int k = f * 32 + quad * 8 + j;
            w1p[f * 8 + j] = pk(W1[k], W1[HID + k]);
            b1v[f * 8 + j] = b1[k];
        }
    half8v bf[4][2];
#pragma unroll
    for (int t = 0; t < 4; t++)
#pragma unroll
        for (int f = 0; f < 2; f++) {
            union { half8v v; uint uu[4]; } tmp;
#pragma unroll
            for (int jj = 0; jj < 4; jj++) {
                const int k0 = f * 32 + quad * 8 + 2 * jj;
                const int n  = t * 16 + l15;
                tmp.uu[jj] = __builtin_bit_cast(uint,
                    pk(W2[k0 * HID + n], W2[(k0 + 1) * HID + n]));
            }
            bf[t][f] = tmp.v;
        }
    float b2f[4], w3a[4], w3b[4];
#pragma unroll
    for (int t = 0; t < 4; t++) {
        const int n = t * 16 + l15;
        b2f[t] = b2[n];
        w3a[t] = W3[2 * n];
        w3b[t] = W3[2 * n + 1];
    }

    // ---- phase 1: strain invariants per element, activations to LDS ----
    float d00s[4], d11s[4], d01s[4], rds[4], wgt4[4];
    int ed[8];
    uint4 xq = make_uint4(0u, 0u, 0u, 0u);
    if (valid) {
        const int4 c4 = ((const int4*)conn)[e];
        ed[0] = 2 * c4.x; ed[1] = ed[0] + 1;
        ed[2] = 2 * c4.y; ed[3] = ed[2] + 1;
        ed[4] = 2 * c4.z; ed[5] = ed[4] + 1;
        ed[6] = 2 * c4.w; ed[7] = ed[6] + 1;
        float ue[8];
#pragma unroll
        for (int j = 0; j < 8; j++) ue[j] = weight1[ed[j]] * u[ed[j]];

        const float4 jv = ((const float4*)Jacc)[e];
        const float4 gw = ((const float4*)gp_w)[0];
        wgt4[0] = jv.x * gw.x; wgt4[1] = jv.y * gw.y;
        wgt4[2] = jv.z * gw.z; wgt4[3] = jv.w * gw.w;

        uint xs[4];
#pragma unroll
        for (int g = 0; g < NGP; g++) {
            const float4* Bp = (const float4*)(B + ((size_t)e * NGP + g) * 24);
            float Bg[24];
#pragma unroll
            for (int t2 = 0; t2 < 6; t2++) {
                float4 v = Bp[t2];
                Bg[4 * t2 + 0] = v.x; Bg[4 * t2 + 1] = v.y;
                Bg[4 * t2 + 2] = v.z; Bg[4 * t2 + 3] = v.w;
            }
            float s0 = 0.f, s1 = 0.f, s2 = 0.f;
#pragma unroll
            for (int j = 0; j < 8; j++) {
                s0 = fmaf(Bg[j],      ue[j], s0);
                s1 = fmaf(Bg[8 + j],  ue[j], s1);
                s2 = fmaf(Bg[16 + j], ue[j], s2);
            }
            const float ev  = s0 + s1;
            const float ev3 = ev * (1.0f / 3.0f);
            const float d00 = s0 - ev3, d11 = s1 - ev3, d22 = -ev3, d01 = 0.5f * s2;
            const float det = sqrtf(d00 * d00 + d11 * d11 + d22 * d22 + 2.0f * d01 * d01);
            const float rd  = __builtin_amdgcn_rcpf(det);
            const float es  = det * SQ23;
            d00s[g] = d00; d11s[g] = d11; d01s[g] = d01; rds[g] = rd;
            xs[g] = __builtin_bit_cast(uint, pk(fmaf(ev, si0, li0), fmaf(es, si1, li1)));
        }
        xq = make_uint4(xs[0], xs[1], xs[2], xs[3]);
    }
    ((uint4*)sX)[tid] = xq;   // invalid lanes write zeros
    __syncthreads();

    // ---- phase 2: wave-level MFMA MLP over this wave's 256 GP-rows ----
#pragma unroll 1
    for (int rt = 0; rt < 16; rt++) {
        const int tb = wv * 256 + rt * 16;
        const half2v xp = __builtin_bit_cast(half2v, sX[tb + l15]);

        union { half8v v; uint uu[4]; } A0, A1;
#pragma unroll
        for (int jj = 0; jj < 4; jj++) {
            const float t0 = fast_tanh(fdot2(xp, w1p[2 * jj],     b1v[2 * jj]));
            const float t1 = fast_tanh(fdot2(xp, w1p[2 * jj + 1], b1v[2 * jj + 1]));
            const float t2 = fast_tanh(fdot2(xp, w1p[8 + 2 * jj],     b1v[8 + 2 * jj]));
            const float t3 = fast_tanh(fdot2(xp, w1p[8 + 2 * jj + 1], b1v[8 + 2 * jj + 1]));
            A0.uu[jj] = __builtin_bit_cast(uint, pk(t0, t1));
            A1.uu[jj] = __builtin_bit_cast(uint, pk(t2, t3));
        }

        float s0[4] = {0.f, 0.f, 0.f, 0.f};
        float s1[4] = {0.f, 0.f, 0.f, 0.f};
#pragma unroll
        for (int t = 0; t < 4; t++) {
            float4v c = {b2f[t], b2f[t], b2f[t], b2f[t]};
            c = __builtin_amdgcn_mfma_f32_16x16x32_f16(A0.v, bf[t][0], c, 0, 0, 0);
            c = __builtin_amdgcn_mfma_f32_16x16x32_f16(A1.v, bf[t][1], c, 0, 0, 0);
#pragma unroll
            for (int reg = 0; reg < 4; reg++) {
                const float h = fast_tanh(c[reg]);
                s0[reg] = fmaf(h, w3a[t], s0[reg]);
                s1[reg] = fmaf(h, w3b[t], s1[reg]);
            }
        }
#pragma unroll
        for (int mask = 1; mask < 16; mask <<= 1) {
#pragma unroll
            for (int reg = 0; reg < 4; reg++) {
                s0[reg] += __shfl_xor(s0[reg], mask, 64);
                s1[reg] += __shfl_xor(s1[reg], mask, 64);
            }
        }
        if (l15 < 4) {
            float a = s0[0], b = s1[0];
            if (l15 == 1) { a = s0[1]; b = s1[1]; }
            if (l15 == 2) { a = s0[2]; b = s1[2]; }
            if (l15 == 3) { a = s0[3]; b = s1[3]; }
            const int gi = tb + quad * 4 + l15;
            sG[gi & 3][gi >> 2] = make_float2(a, b);
        }
    }
    __syncthreads();

    // ---- phase 3: stress -> E_P -> fused scatter ----
    if (valid) {
        float EP[8] = {0.f, 0.f, 0.f, 0.f, 0.f, 0.f, 0.f, 0.f};
#pragma unroll
        for (int g = 0; g < NGP; g++) {
            const float2 gv = sG[g][tid];
            const float p = (gv.x + b30 - lg0) * isg0;
            const float q = (gv.y + b31 - lg1) * isg1;
            const float crd = SQ23 * q * rds[g];
            const float f0 = fmaf(crd, d00s[g], p) * wgt4[g];
            const float f1 = fmaf(crd, d11s[g], p) * wgt4[g];
            const float f2 = (crd * d01s[g]) * wgt4[g];
            const float4* Bp = (const float4*)(B + ((size_t)e * NGP + g) * 24);
            float4 v0 = Bp[0], v1 = Bp[1], v2 = Bp[2], v3 = Bp[3], v4 = Bp[4], v5 = Bp[5];
            EP[0] = fmaf(v0.x, f0, fmaf(v2.x, f1, fmaf(v4.x, f2, EP[0])));
            EP[1] = fmaf(v0.y, f0, fmaf(v2.y, f1, fmaf(v4.y, f2, EP[1])));
            EP[2] = fmaf(v0.z, f0, fmaf(v2.z, f1, fmaf(v4.z, f2, EP[2])));
            EP[3] = fmaf(v0.w, f0, fmaf(v2.w, f1, fmaf(v4.w, f2, EP[3])));
            EP[4] = fmaf(v1.x, f0, fmaf(v3.x, f1, fmaf(v5.x, f2, EP[4])));
            EP[5] = fmaf(v1.y, f0, fmaf(v3.y, f1, fmaf(v5.y, f2, EP[5])));
            EP[6] = fmaf(v1.z, f0, fmaf(v3.z, f1, fmaf(v5.z, f2, EP[6])));
            EP[7] = fmaf(v1.w, f0, fmaf(v3.w, f1, fmaf(v5.w, f2, EP[7])));
        }
        atomic_add2(&F[ed[0]], EP[0], EP[1]);
        atomic_add2(&F[ed[2]], EP[2], EP[3]);
        atomic_add2(&F[ed[4]], EP[4], EP[5]);
        atomic_add2(&F[ed[6]], EP[6], EP[7]);
    }
}

extern "C" void kernel_launch(void* const* d_in, const int* in_sizes, int n_in,
                              void* d_out, int out_size, void* d_ws, size_t ws_size,
                              hipStream_t stream) {
    const float* u           = (const float*)d_in[0];
    const float* B           = (const float*)d_in[1];
    const float* Jacc        = (const float*)d_in[2];
    const float* gp_w        = (const float*)d_in[3];
    const int*   conn        = (const int*)  d_in[4];
    const float* weight1     = (const float*)d_in[5];
    const float* scales_inp  = (const float*)d_in[6];
    const float* limits_inp  = (const float*)d_in[7];
    const float* scales_grad = (const float*)d_in[8];
    const float* limits_grad = (const float*)d_in[9];
    const float* W1          = (const float*)d_in[10];
    const float* b1          = (const float*)d_in[11];
    const float* W2          = (const float*)d_in[12];
    const float* b2          = (const float*)d_in[13];
    const float* W3          = (const float*)d_in[14];
    const float* b3          = (const float*)d_in[15];
    float* F = (float*)d_out;

    (void)hipMemsetAsync(d_out, 0, sizeof(float) * NDOF, stream);

    const int grid = (NELEM + 255) / 256;
    fem_force_kernel<<<grid, 256, 0, stream>>>(
        u, B, Jacc, gp_w, conn, weight1, scales_inp, limits_inp,
        scales_grad, limits_grad, W1, b1, W2, b2, W3, b3, F);
}